// Round 1
// baseline (212.985 us; speedup 1.0000x reference)
//
#include <hip/hip_runtime.h>

// BinaryMatchAttention: out[b,d] = sum_s prod_k(1-|x[b,s,96+k]-qbit[k]|) * x[b,s,d], d<96
// x: (8, 32768, 128) fp32, query_addr: int scalar, out: (8, 96) fp32.

constexpr int B = 8;
constexpr int S = 32768;
constexpr int D4 = 32;            // float4 columns per row (128 floats)
constexpr int VAL4 = 24;          // value float4 columns (96 floats)
constexpr int ROWS_PER_STEP = 8;  // 256 threads / 32 columns
constexpr int BLOCKS_PER_B = 256;
constexpr int SPB = S / BLOCKS_PER_B;  // 128 rows per block

__global__ __launch_bounds__(256)
void bma_kernel(const float* __restrict__ x, const int* __restrict__ qaddr,
                float* __restrict__ out) {
    const int t    = threadIdx.x;
    const int c    = t & 31;        // float4 column
    const int rg   = t >> 5;        // row group 0..7
    const int lane = t & 63;
    const int b    = blockIdx.x / BLOCKS_PER_B;
    const int s0   = (blockIdx.x % BLOCKS_PER_B) * SPB;

    const unsigned qa = (unsigned)qaddr[0];
    // query bits for the 4 elements held by lanes c=24..27
    float qb0 = 0.f, qb1 = 0.f, qb2 = 0.f, qb3 = 0.f;
    if (c >= 24 && c < 28) {
        const int k0 = (c - 24) * 4;
        qb0 = (float)((qa >> (k0 + 0)) & 1u);
        qb1 = (float)((qa >> (k0 + 1)) & 1u);
        qb2 = (float)((qa >> (k0 + 2)) & 1u);
        qb3 = (float)((qa >> (k0 + 3)) & 1u);
    }

    const float4* __restrict__ xb =
        reinterpret_cast<const float4*>(x) + (long)b * S * D4;
    const int src = (lane & 32) | 24;  // broadcast source lane for this row

    float4 acc = make_float4(0.f, 0.f, 0.f, 0.f);

    for (int s = s0 + rg; s < s0 + SPB; s += ROWS_PER_STEP) {
        float4 v = make_float4(0.f, 0.f, 0.f, 0.f);
        if (c < 28) v = xb[(long)s * D4 + c];   // skip dead cols 112..127

        float p = 1.0f;
        if (c >= 24 && c < 28) {
            p = (1.0f - fabsf(v.x - qb0)) * (1.0f - fabsf(v.y - qb1)) *
                (1.0f - fabsf(v.z - qb2)) * (1.0f - fabsf(v.w - qb3));
        }
        // product across the aligned 4-lane group {24..27} / {56..59}
        p *= __shfl_xor(p, 1);
        p *= __shfl_xor(p, 2);
        const float w = __shfl(p, src, 64);     // broadcast to the row's lanes

        if (c < VAL4) {
            acc.x = fmaf(w, v.x, acc.x);
            acc.y = fmaf(w, v.y, acc.y);
            acc.z = fmaf(w, v.z, acc.z);
            acc.w = fmaf(w, v.w, acc.w);
        }
    }

    // reduce the 8 row-groups
    __shared__ float4 red[256];
    red[t] = acc;
    __syncthreads();
    if (t < 32) {
        float4 sum = red[t];
        #pragma unroll
        for (int g = 1; g < 8; ++g) {
            float4 o = red[t + 32 * g];
            sum.x += o.x; sum.y += o.y; sum.z += o.z; sum.w += o.w;
        }
        if (t < VAL4) {
            float* op = out + b * 96 + t * 4;
            atomicAdd(op + 0, sum.x);
            atomicAdd(op + 1, sum.y);
            atomicAdd(op + 2, sum.z);
            atomicAdd(op + 3, sum.w);
        }
    }
}

extern "C" void kernel_launch(void* const* d_in, const int* in_sizes, int n_in,
                              void* d_out, int out_size, void* d_ws, size_t ws_size,
                              hipStream_t stream) {
    const float* x  = (const float*)d_in[0];
    const int*   qa = (const int*)d_in[1];
    float*       out = (float*)d_out;

    // d_out is poisoned 0xAA before every call — zero it (graph-capturable).
    hipMemsetAsync(out, 0, (size_t)out_size * sizeof(float), stream);

    bma_kernel<<<dim3(B * BLOCKS_PER_B), dim3(256), 0, stream>>>(x, qa, out);
}

// Round 2
// 193.520 us; speedup vs baseline: 1.1006x; 1.1006x over previous
//
#include <hip/hip_runtime.h>

// BinaryMatchAttention: out[b,d] = sum_s prod_k(1-|x[b,s,96+k]-qbit[k]|) * x[b,s,d], d<96
// x: (8, 32768, 128) fp32, query_addr: int scalar, out: (8, 96) fp32.
//
// Two-stage: stage 1 streams x, writes per-block 96-float partials to d_ws;
// stage 2 reduces 256 partials per batch and writes d_out (no atomics, no memset).

constexpr int B = 8;
constexpr int S = 32768;
constexpr int D4 = 32;            // float4 columns per row (128 floats)
constexpr int VAL4 = 24;          // value float4 columns (96 floats)
constexpr int ROWS_PER_STEP = 8;  // 256 threads / 32 columns
constexpr int BLOCKS_PER_B = 256;
constexpr int SPB = S / BLOCKS_PER_B;  // 128 rows per block

__global__ __launch_bounds__(256)
void bma_stage1(const float* __restrict__ x, const int* __restrict__ qaddr,
                float* __restrict__ partial) {
    const int t    = threadIdx.x;
    const int c    = t & 31;        // float4 column
    const int rg   = t >> 5;        // row group 0..7
    const int lane = t & 63;
    const int b    = blockIdx.x / BLOCKS_PER_B;
    const int s0   = (blockIdx.x % BLOCKS_PER_B) * SPB;

    const unsigned qa = (unsigned)qaddr[0];
    float qb0 = 0.f, qb1 = 0.f, qb2 = 0.f, qb3 = 0.f;
    if (c >= 24 && c < 28) {
        const int k0 = (c - 24) * 4;
        qb0 = (float)((qa >> (k0 + 0)) & 1u);
        qb1 = (float)((qa >> (k0 + 1)) & 1u);
        qb2 = (float)((qa >> (k0 + 2)) & 1u);
        qb3 = (float)((qa >> (k0 + 3)) & 1u);
    }

    const float4* __restrict__ xb =
        reinterpret_cast<const float4*>(x) + (long)b * S * D4;
    const int src = (lane & 32) | 24;  // broadcast source lane for this row

    float4 acc = make_float4(0.f, 0.f, 0.f, 0.f);

    #pragma unroll 4
    for (int i = 0; i < SPB / ROWS_PER_STEP; ++i) {
        const int s = s0 + rg + i * ROWS_PER_STEP;
        float4 v = make_float4(0.f, 0.f, 0.f, 0.f);
        if (c < 28) v = xb[(long)s * D4 + c];   // skip dead cols 112..127

        float p = 1.0f;
        if (c >= 24 && c < 28) {
            p = (1.0f - fabsf(v.x - qb0)) * (1.0f - fabsf(v.y - qb1)) *
                (1.0f - fabsf(v.z - qb2)) * (1.0f - fabsf(v.w - qb3));
        }
        // product across the aligned 4-lane group {24..27} / {56..59}
        p *= __shfl_xor(p, 1);
        p *= __shfl_xor(p, 2);
        const float w = __shfl(p, src, 64);     // broadcast to the row's lanes

        if (c < VAL4) {
            acc.x = fmaf(w, v.x, acc.x);
            acc.y = fmaf(w, v.y, acc.y);
            acc.z = fmaf(w, v.z, acc.z);
            acc.w = fmaf(w, v.w, acc.w);
        }
    }

    // reduce the 8 row-groups, write 96-float partial for this block
    __shared__ float4 red[256];
    red[t] = acc;
    __syncthreads();
    if (t < 32) {
        float4 sum = red[t];
        #pragma unroll
        for (int g = 1; g < 8; ++g) {
            float4 o = red[t + 32 * g];
            sum.x += o.x; sum.y += o.y; sum.z += o.z; sum.w += o.w;
        }
        if (t < VAL4) {
            float4* pp = reinterpret_cast<float4*>(partial) + (long)blockIdx.x * VAL4 + t;
            *pp = sum;
        }
    }
}

// partial: [B*BLOCKS_PER_B][96] floats. out: [B][96].
__global__ __launch_bounds__(256)
void bma_stage2(const float* __restrict__ partial, float* __restrict__ out) {
    const int t  = threadIdx.x;
    const int c  = t & 31;   // float4 column (0..23 active)
    const int rg = t >> 5;   // chunk group 0..7
    const int b  = blockIdx.x;

    const float4* __restrict__ pp =
        reinterpret_cast<const float4*>(partial) + (long)b * BLOCKS_PER_B * VAL4;

    float4 acc = make_float4(0.f, 0.f, 0.f, 0.f);
    if (c < VAL4) {
        #pragma unroll 4
        for (int chunk = rg; chunk < BLOCKS_PER_B; chunk += ROWS_PER_STEP) {
            float4 v = pp[(long)chunk * VAL4 + c];
            acc.x += v.x; acc.y += v.y; acc.z += v.z; acc.w += v.w;
        }
    }

    __shared__ float4 red[256];
    red[t] = acc;
    __syncthreads();
    if (t < VAL4) {
        float4 sum = red[t];
        #pragma unroll
        for (int g = 1; g < 8; ++g) {
            float4 o = red[t + 32 * g];
            sum.x += o.x; sum.y += o.y; sum.z += o.z; sum.w += o.w;
        }
        reinterpret_cast<float4*>(out)[(long)b * VAL4 + t] = sum;
    }
}

extern "C" void kernel_launch(void* const* d_in, const int* in_sizes, int n_in,
                              void* d_out, int out_size, void* d_ws, size_t ws_size,
                              hipStream_t stream) {
    const float* x   = (const float*)d_in[0];
    const int*   qa  = (const int*)d_in[1];
    float*       out = (float*)d_out;
    float*       ws  = (float*)d_ws;   // needs B*BLOCKS_PER_B*96*4 = 768 KiB

    bma_stage1<<<dim3(B * BLOCKS_PER_B), dim3(256), 0, stream>>>(x, qa, ws);
    bma_stage2<<<dim3(B), dim3(256), 0, stream>>>(ws, out);
}